// Round 9
// baseline (154.539 us; speedup 1.0000x reference)
//
#include <hip/hip_runtime.h>

typedef __attribute__((ext_vector_type(8))) __bf16 bf16x8;
typedef __attribute__((ext_vector_type(4))) float f32x4;
typedef __attribute__((ext_vector_type(8))) unsigned short u16x8;
typedef unsigned short u16;
typedef unsigned int u32;

#define NB 524288
#define EPSI 1e-5f
#define NSHADOW 16   // sharded stat accumulators: 16 x 128 floats
#define K_LOG2E 1.4426950408889634f

// 2-dispatch structure (R5: grid-wide counter election = ~32 us serialized RMWs;
// R2-R4: separate 1-block finalize dispatch = ~6-8 us. Both avoided.)
//
// ws byte layout:
//   [0, 8192)       : 16 shard copies of the 128 stat floats (sum, sumsq)
//   [16384, 28672)  : w2 frags, 768 slots x 16 B, FINAL slot order
//                     (fi/fs cols even/odd-paired, fi AND fs pre-scaled by
//                     log2e, u/v leaf-pairs folded) -- packed by stats blk 0-2
//   [28672, 30208)  : biasv, 384 f32 (96 biases broadcast x4, GEMM2 C layout)
//                     -- packed by stats blk 3
// Stats-pack is stats-INDEPENDENT work -> no intra-kernel ordering needed.
// Cross-kernel visibility via dispatch boundary.
//
// R6: main latency-bound -> amortize prologue + pipeline a1 (R7: 151.5 best).
// R8 (noise): deeper prefetch didn't move. R9: VGPR audit shows main <=64 VGPR
// (a1 frag = 4 VGPRs, not 16) -> grid was the occupancy limiter, not regs.
// main: 2048 blocks x 4 tiles = 8 blocks/CU (LDS 18944x8=151.5KB fits).
// stats: 1024 blocks x 2 halves -> per-block tail + atomics halved.

__device__ __forceinline__ float bf2f(u16 h) {
    union { u32 u; float f; } cv; cv.u = ((u32)h) << 16; return cv.f;
}
__device__ __forceinline__ u16 f2bf(float f) {
    __bf16 b = (__bf16)f; return __builtin_bit_cast(u16, b);
}
__device__ __forceinline__ float ldany(const void* p, long i, int isf) {
    return isf ? ((const float*)p)[i] : bf2f(((const u16*)p)[i]);
}

#if __has_builtin(__builtin_amdgcn_exp2f)
#define EXP2F(x) __builtin_amdgcn_exp2f(x)
#else
#define EXP2F(x) exp2f(x)
#endif

// gelu_tanh with log2e folded into the polynomial:
// g = v / (1 + exp2(-v*(GK1 + GK2*v^2))), GK1 = 1.5957691*log2e, GK2 = GK1*0.044715
#define GK1 2.3022082f
#define GK2 0.10294324f
__device__ __forceinline__ float fast_gelu(float v) {
    float t2 = v * fmaf(GK2, v * v, GK1);
    float en = EXP2F(-t2);
    return v * __builtin_amdgcn_rcpf(1.0f + en);
}

__device__ __forceinline__ bf16x8 loadfrag(const __bf16* p) {
    return *reinterpret_cast<const bf16x8*>(p);
}
__device__ __forceinline__ bf16x8 loadfrag(const float* p) {
    f32x4 a = *reinterpret_cast<const f32x4*>(p);
    f32x4 b = *reinterpret_cast<const f32x4*>(p + 4);
    bf16x8 r;
#pragma unroll
    for (int i = 0; i < 4; ++i) { r[i] = (__bf16)a[i]; r[4 + i] = (__bf16)b[i]; }
    return r;
}

template<typename T>
__device__ __forceinline__ void load8f(const T* p, float* o);
template<>
__device__ __forceinline__ void load8f<__bf16>(const __bf16* p, float* o) {
    bf16x8 r = *reinterpret_cast<const bf16x8*>(p);
#pragma unroll
    for (int i = 0; i < 8; ++i) o[i] = (float)r[i];
}
template<>
__device__ __forceinline__ void load8f<float>(const float* p, float* o) {
    f32x4 a = *reinterpret_cast<const f32x4*>(p);
    f32x4 b = *reinterpret_cast<const f32x4*>(p + 4);
#pragma unroll
    for (int i = 0; i < 4; ++i) { o[i] = a[i]; o[4 + i] = b[i]; }
}

// paired epilogue-x load: features 2c and 2c+1 are adjacent in memory
__device__ __forceinline__ void load2f(const float* p, float& a, float& b) {
    const float2 v = *reinterpret_cast<const float2*>(p);
    a = v.x; b = v.y;
}
__device__ __forceinline__ void load2f(const __bf16* p, float& a, float& b) {
    u32 w = *reinterpret_cast<const u32*>(p);
    a = bf2f((u16)(w & 0xffffu)); b = bf2f((u16)(w >> 16));
}

// Per-wave dtype self-detect (f32-as-u16 low halves: ~25% have bf16-exp>=0xC0; true
// bf16 N(0,1): none). P(miss) < 1e-14 over 128 samples.
__device__ __forceinline__ int detect_isf(const void* x) {
    const int lane = threadIdx.x & 63;
    u32 w0 = ((const u32*)x)[lane];
    u32 w1 = ((const u32*)x)[64 + lane];
    int hit = ((((w0 >> 7) & 0xFFu) >= 0xC0u) || (((w1 >> 7) & 0xFFu) >= 0xC0u)) ? 1 : 0;
    return __ballot(hit) != 0ull;
}

// VALU-pipe rotation-add over each 16-lane row (DPP row_ror:N)
template<int CTRL>
__device__ __forceinline__ float dpp_rot_add(float v) {
    int s = __builtin_amdgcn_update_dpp(0, __builtin_bit_cast(int, v), CTRL, 0xF, 0xF, false);
    return v + __builtin_bit_cast(float, s);
}
__device__ __forceinline__ float row_reduce_add(float v) {
    v = dpp_rot_add<0x121>(v);   // row_ror:1
    v = dpp_rot_add<0x122>(v);   // row_ror:2
    v = dpp_rot_add<0x124>(v);   // row_ror:4
    v = dpp_rot_add<0x128>(v);   // row_ror:8
    return v;
}

// ---- stats: column sums/sumsq of h_pre = x @ w_in^T into 16 sharded copies.
// 2 halves x 4 hoisted tile loads (64 B/lane in flight); accumulators persist
// across halves; one reduction tail per block (half the blocks of R8).
template<typename T>
__device__ __forceinline__ void stats_body(const T* __restrict__ x,
                                           const T* __restrict__ w_in,
                                           float* __restrict__ ws,
                                           float* __restrict__ red) {
    const int lane = threadIdx.x & 63;
    const int wave = threadIdx.x >> 6;
    const int c = lane & 15;
    const int q = lane >> 4;

    const long wid0 = (long)blockIdx.x * 4 + wave;  // 0..4095, 128 rows each

    bf16x8 b1[4];
#pragma unroll
    for (int nt = 0; nt < 4; ++nt)
        b1[nt] = loadfrag(w_in + (nt * 16 + c) * 32 + q * 8);

    float accs[4][4], accq[4][4];
#pragma unroll
    for (int nt = 0; nt < 4; ++nt)
#pragma unroll
        for (int r = 0; r < 4; ++r) { accs[nt][r] = 0.f; accq[nt][r] = 0.f; }

#pragma unroll
    for (int half = 0; half < 2; ++half) {
        // issue all 4 tile loads first
        bf16x8 a1[4];
#pragma unroll
        for (int t = 0; t < 4; ++t) {
            const long row0 = wid0 * 128 + half * 64 + t * 16;
            a1[t] = loadfrag(x + (row0 + c) * 32 + q * 8);
        }
#pragma unroll
        for (int t = 0; t < 4; ++t) {
#pragma unroll
            for (int nt = 0; nt < 4; ++nt) {
                f32x4 z = {0.f, 0.f, 0.f, 0.f};
                f32x4 acc = __builtin_amdgcn_mfma_f32_16x16x32_bf16(a1[t], b1[nt], z, 0, 0, 0);
#pragma unroll
                for (int r = 0; r < 4; ++r) {
                    float v = acc[r];
                    accs[nt][r] += v;
                    accq[nt][r] += v * v;
                }
            }
        }
    }
    for (int i = threadIdx.x; i < 128; i += 256) red[i] = 0.f;
    __syncthreads();
#pragma unroll
    for (int nt = 0; nt < 4; ++nt) {
        float s  = accs[nt][0] + accs[nt][1] + accs[nt][2] + accs[nt][3];
        float sq = accq[nt][0] + accq[nt][1] + accq[nt][2] + accq[nt][3];
        s  += __shfl_xor(s, 16);  s  += __shfl_xor(s, 32);
        sq += __shfl_xor(sq, 16); sq += __shfl_xor(sq, 32);
        if (q == 0) {
            atomicAdd(&red[nt * 16 + c], s);
            atomicAdd(&red[64 + nt * 16 + c], sq);
        }
    }
    __syncthreads();
    float* shard = ws + (blockIdx.x & (NSHADOW - 1)) * 128;
    for (int i = threadIdx.x; i < 128; i += 256) atomicAdd(&shard[i], red[i]);
}

__global__ __launch_bounds__(256) void stats_kernel(
    const void* x, const void* w_in,
    const void* w_fi, const void* b_fi, const void* w_fs, const void* b_fs,
    const void* w_lc, const void* b_lc, float* __restrict__ ws)
{
    const int isf = detect_isf(x);
    const int tid = threadIdx.x;

    // stats-independent weight pack (blocks 0-3): w2 frags in FINAL slot order.
    if (blockIdx.x < 3) {
        const int k = blockIdx.x * 256 + tid;            // 0..767
        const int f = k >> 6, l = k & 63, cc = l & 15, qq = l >> 4;
        const int nt = f >> 1, kt = f & 1;
        const int hb = kt * 32 + qq * 8;
        u16x8 v8;
        if (nt < 2) {
            const int ft = 2 * cc + nt;
#pragma unroll
            for (int j = 0; j < 8; ++j)
                v8[j] = f2bf(ldany(w_fi, ft * 64 + hb + j, isf) * K_LOG2E);
        } else if (nt < 4) {
            const int ft = 2 * cc + (nt - 2);
#pragma unroll
            for (int j = 0; j < 8; ++j)
                v8[j] = f2bf(ldany(w_fs, ft * 64 + hb + j, isf) * K_LOG2E);
        } else {
            const int r0 = ((nt == 4) ? 0 : 20) + cc;
#pragma unroll
            for (int j = 0; j < 8; ++j)
                v8[j] = (cc < 10) ? f2bf(ldany(w_lc, (long)r0 * 64 + hb + j, isf)
                                       + ldany(w_lc, (long)(r0 + 10) * 64 + hb + j, isf))
                                  : (u16)0;
        }
        *reinterpret_cast<u16x8*>((u16*)((char*)ws + 16384) + k * 8) = v8;
    } else if (blockIdx.x == 3) {
        float* biasp = (float*)((char*)ws + 28672);
        for (int idx = tid; idx < 384; idx += 256) {
            const int p = idx >> 2, nt = p >> 4, cc = p & 15;
            float v = 0.f;
            if      (nt == 0) v = ldany(b_fi, 2 * cc,     isf) * K_LOG2E;
            else if (nt == 1) v = ldany(b_fi, 2 * cc + 1, isf) * K_LOG2E;
            else if (nt == 2) v = ldany(b_fs, 2 * cc,     isf) * K_LOG2E;
            else if (nt == 3) v = ldany(b_fs, 2 * cc + 1, isf) * K_LOG2E;
            else if (nt == 4) v = (cc < 10) ? ldany(b_lc, cc,      isf) + ldany(b_lc, 10 + cc, isf) : 0.f;
            else              v = (cc < 10) ? ldany(b_lc, 20 + cc, isf) + ldany(b_lc, 30 + cc, isf) : 0.f;
            biasp[idx] = v;
        }
    }

    __shared__ float red[128];
    if (isf) stats_body<float>((const float*)x, (const float*)w_in, ws, red);
    else     stats_body<__bf16>((const __bf16*)x, (const __bf16*)w_in, ws, red);
    // fence-free end: no election, no tail. Dispatch boundary publishes everything.
}

// ---- main: per-block prologue (2 barriers) then 4 software-pipelined tiles.
// GEMM1 transposed (A=scaled-W1 rows permuted by phi, B=x^T) so its C-layout
// output IS the A-fragment of GEMM2. BN shift rides GEMM1's C operand; GEMM2
// biases ride GEMM2's C operand. fi/fs pre-scaled by log2e -> bare v_exp.
// a1 prefetch depth 2; xv loads L1-hot on lines a1 warmed 2 tiles earlier.
template<typename T>
__device__ __forceinline__ void main_body(
    const T* __restrict__ x, const T* __restrict__ w_in,
    const T* __restrict__ bn_g, const T* __restrict__ bn_b,
    const float* __restrict__ ws, T* __restrict__ out,
    char* __restrict__ lds, float* __restrict__ sums,
    float* __restrict__ shs)
{
    const int tid = threadIdx.x;
    const int lane = tid & 63;
    const int wave = tid >> 6;
    const int c = lane & 15;
    const int q = lane >> 4;

    const long gw = (long)blockIdx.x * 4 + wave;   // 0..8191, 64 rows each
    const long rowb = gw * 64;

    // issue tiles 0 and 1's a1 immediately (hide under the whole prologue)
    bf16x8 a1cur = loadfrag(x + (rowb + c) * 32 + q * 8);
    bf16x8 a1nx1 = loadfrag(x + (rowb + 16 + c) * 32 + q * 8);

    // phase A: linear copy of stats-packed w2+bias blob (13824 B = 864 x 16 B)
    // and collapse of the 16 sharded stat copies. Independent, no barrier between.
    {
        const f32x4* gsrc = (const f32x4*)((const char*)ws + 16384);
        f32x4* ldst = (f32x4*)(lds + 4096);
        for (int i = tid; i < 864; i += 256) ldst[i] = gsrc[i];
    }
    if (tid < 128) {
        float s = 0.f;
#pragma unroll
        for (int k = 0; k < NSHADOW; ++k) s += ws[k * 128 + tid];
        sums[tid] = s;
    }
    __syncthreads();

    // phase B: w1 scale-pack with INLINE scl (each thread recomputes its row's
    // BN scale from sums); shs (C-operand-layout BN shifts) by tid<64.
    {
        const int nt = tid >> 6, l = tid & 63, cc = l & 15, qq = l >> 4;
        const int row = 32 * (nt >> 1) + 8 * (cc >> 2) + 4 * (nt & 1) + (cc & 3);
        float mu  = sums[row] * (1.0f / NB);
        float var = fmaxf(sums[64 + row] * (1.0f / NB) - mu * mu, 0.0f);
        float s   = (float)bn_g[row] * rsqrtf(var + EPSI);
        float w8[8];
        load8f(w_in + row * 32 + qq * 8, w8);
        u16x8 v8;
#pragma unroll
        for (int j = 0; j < 8; ++j) v8[j] = f2bf(w8[j] * s);
        *reinterpret_cast<u16x8*>(lds + tid * 16) = v8;
    }
    if (tid < 64) {
        const int qq = tid >> 4, nt = (tid >> 2) & 3, r = tid & 3;
        const int ft = 32 * (nt >> 1) + 8 * qq + 4 * (nt & 1) + r;
        float mu  = sums[ft] * (1.0f / NB);
        float var = fmaxf(sums[64 + ft] * (1.0f / NB) - mu * mu, 0.0f);
        float s   = (float)bn_g[ft] * rsqrtf(var + EPSI);
        shs[tid] = (float)bn_b[ft] - mu * s;
    }
    __syncthreads();

    // phase C: persistent w1 fragments, then the pipelined tile loop
    bf16x8 w1r[4];
#pragma unroll
    for (int nt = 0; nt < 4; ++nt)
        w1r[nt] = *reinterpret_cast<const bf16x8*>((const u16*)lds + (nt * 64 + lane) * 8);

#pragma unroll
    for (int t = 0; t < 4; ++t) {
        // prefetch tile t+2's a1 (B-frag of GEMM1)
        bf16x8 a1nx2;
        if (t < 2) a1nx2 = loadfrag(x + (rowb + (long)(t + 2) * 16 + c) * 32 + q * 8);

        // opaque zero offset: stops the compiler hoisting the LARGE LDS arrays
        // (w2/sh/bias) back into persistent registers across tiles
        u32 tweak = 0;
        asm volatile("" : "+v"(tweak));
        const u16*   w2b = (const u16*)(lds + 4096) + tweak;
        const float* bb  = (const float*)(lds + 16384) + tweak;
        const float* shb = shs + tweak;

        const long row0 = rowb + (long)t * 16;

        // epilogue x pairs (features 2c, 2c+1) in C-layout; L1-hot (a1-warmed)
        float xv0[4], xv1[4];
#pragma unroll
        for (int r = 0; r < 4; ++r)
            load2f(x + (row0 + q * 4 + r) * 32 + 2 * c, xv0[r], xv1[r]);

        // GEMM1^T with BN shift as the C operand:
        // lane(c,q) reg r = s*h_pre[batch c][feat phi(nt,4q+r)] + shift(...)
        f32x4 h4[4];
#pragma unroll
        for (int nt = 0; nt < 4; ++nt) {
            f32x4 sh = *reinterpret_cast<const f32x4*>(shb + q * 16 + nt * 4);
            h4[nt] = __builtin_amdgcn_mfma_f32_16x16x32_bf16(w1r[nt], a1cur, sh, 0, 0, 0);
        }

        // gelu; pack: a2_0[j=4nt+r]=g[nt][r] (nt 0..1), a2_1: nt 2..3
        bf16x8 a2_0, a2_1;
#pragma unroll
        for (int nt = 0; nt < 2; ++nt) {
#pragma unroll
            for (int r = 0; r < 4; ++r) {
                a2_0[nt * 4 + r] = (__bf16)fast_gelu(h4[nt][r]);
                a2_1[nt * 4 + r] = (__bf16)fast_gelu(h4[2 + nt][r]);
            }
        }

        // GEMM2 with bias as the C operand
        f32x4 acc[6];
#pragma unroll
        for (int nt = 0; nt < 6; ++nt) {
            bf16x8 f0 = *reinterpret_cast<const bf16x8*>(w2b + ((nt * 2 + 0) * 64 + lane) * 8);
            bf16x8 f1 = *reinterpret_cast<const bf16x8*>(w2b + ((nt * 2 + 1) * 64 + lane) * 8);
            f32x4 bz = *reinterpret_cast<const f32x4*>(bb + (nt * 16 + c) * 4);
            acc[nt] = __builtin_amdgcn_mfma_f32_16x16x32_bf16(a2_0, f0, bz, 0, 0, 0);
            acc[nt] = __builtin_amdgcn_mfma_f32_16x16x32_bf16(a2_1, f1, acc[nt], 0, 0, 0);
        }

#pragma unroll
        for (int r = 0; r < 4; ++r) {
            // acc0/1 = log2e*(fi+b): bare exp2. No max-subtraction: |fi| << 87.
            float e0 = EXP2F(acc[0][r]);
            float e1 = EXP2F(acc[1][r]);
            // acc2/3 = log2e*(fs+b): t = log2e*(x - fs), so dp is log2e*<smx, x-fs>
            float t0 = fmaf(K_LOG2E, xv0[r], -acc[2][r]);
            float t1 = fmaf(K_LOG2E, xv1[r], -acc[3][r]);
            float es = row_reduce_add(e0 + e1);
            float dp = row_reduce_add(fmaf(e1, t1, e0 * t0));
            float d2 = dp * __builtin_amdgcn_rcpf(es);          // = log2e * d
            float sd = __builtin_amdgcn_rcpf(1.0f + EXP2F(-d2));
            float o  = sd * fmaf(sd, acc[4][r] - acc[5][r], acc[5][r]); // sd^2 u + sd(1-sd) v
            if (c < 10) out[(row0 + q * 4 + r) * 10 + c] = (T)o;
        }

        a1cur = a1nx1;
        a1nx1 = a1nx2;
    }
}

// (256,4): reg cap 128; actual ~60-64 (a1 frag = 4 VGPRs; pipeline adds 8).
// LDS 18944 B x 8 blocks = 151.5 KB <= 160 KB -> 8 blocks/CU offered.
// Grid 2048 = exactly 8 blocks/CU, one generation, 4 tiles/wave.
__global__ __launch_bounds__(256, 4) void main_kernel(
    const void* x, const void* w_in, const void* bn_g, const void* bn_b,
    const float* __restrict__ ws, void* outv)
{
    __shared__ __attribute__((aligned(16))) char lds[17920];
    __shared__ float sums[128], shs[64];
    if (detect_isf(x))
        main_body<float>((const float*)x, (const float*)w_in, (const float*)bn_g,
                         (const float*)bn_b, ws, (float*)outv, lds, sums, shs);
    else
        main_body<__bf16>((const __bf16*)x, (const __bf16*)w_in, (const __bf16*)bn_g,
                          (const __bf16*)bn_b, ws, (__bf16*)outv, lds, sums, shs);
}

extern "C" void kernel_launch(void* const* d_in, const int* in_sizes, int n_in,
                              void* d_out, int out_size, void* d_ws, size_t ws_size,
                              hipStream_t stream) {
    float* ws = (float*)d_ws;
    hipMemsetAsync(d_ws, 0, 8192, stream);  // zero shard accumulators
    stats_kernel<<<1024, 256, 0, stream>>>(d_in[0], d_in[1],
                                           d_in[5], d_in[6], d_in[7], d_in[8],
                                           d_in[9], d_in[10], ws);
    main_kernel<<<2048, 256, 0, stream>>>(d_in[0], d_in[1], d_in[3], d_in[4],
                                          ws, d_out);
}

// Round 10
// 151.795 us; speedup vs baseline: 1.0181x; 1.0181x over previous
//
#include <hip/hip_runtime.h>

typedef __attribute__((ext_vector_type(8))) __bf16 bf16x8;
typedef __attribute__((ext_vector_type(4))) float f32x4;
typedef __attribute__((ext_vector_type(8))) unsigned short u16x8;
typedef unsigned short u16;
typedef unsigned int u32;

#define NB 524288
#define EPSI 1e-5f
#define NSHADOW 16   // sharded stat accumulators: 16 x 128 floats
#define K_LOG2E 1.4426950408889634f

// 2-dispatch structure (R5: grid-wide counter election = ~32 us serialized RMWs;
// R2-R4: separate 1-block finalize dispatch = ~6-8 us. Both avoided.)
//
// ws byte layout:
//   [0, 8192)       : 16 shard copies of the 128 stat floats (sum, sumsq)
//   [16384, 28672)  : w2 frags, 768 slots x 16 B, FINAL slot order
//   [28672, 30208)  : biasv, 384 f32 (96 biases broadcast x4, GEMM2 C layout)
// Stats-pack (blocks 0-3) is stats-INDEPENDENT. Visibility via dispatch boundary.
//
// R7 (best, 151.5): main 1024x8 pipelined. R8/R9: occupancy & prefetch knobs
// all within noise -> reverted to R7/R8 config.
// R10 lever: L2 RECYCLING. stats (2048 blocks) leaves x resident in per-XCD L2
// (4.1 MB/XCD read by blocks p with XCD=p%8). main block m (XCD m%8) is remapped
// to read exactly stats blocks {a, a+8}, a=16*(m>>3)+(m&7) -- both = m (mod 8)
// -> same-XCD L2 hits (~200cy) instead of HBM misses (~900cy) for main's
// latency-bound x reads. Pure index remap; neutral if dispatch mapping differs.

__device__ __forceinline__ float bf2f(u16 h) {
    union { u32 u; float f; } cv; cv.u = ((u32)h) << 16; return cv.f;
}
__device__ __forceinline__ u16 f2bf(float f) {
    __bf16 b = (__bf16)f; return __builtin_bit_cast(u16, b);
}
__device__ __forceinline__ float ldany(const void* p, long i, int isf) {
    return isf ? ((const float*)p)[i] : bf2f(((const u16*)p)[i]);
}

#if __has_builtin(__builtin_amdgcn_exp2f)
#define EXP2F(x) __builtin_amdgcn_exp2f(x)
#else
#define EXP2F(x) exp2f(x)
#endif

// gelu_tanh with log2e folded into the polynomial:
// g = v / (1 + exp2(-v*(GK1 + GK2*v^2))), GK1 = 1.5957691*log2e, GK2 = GK1*0.044715
#define GK1 2.3022082f
#define GK2 0.10294324f
__device__ __forceinline__ float fast_gelu(float v) {
    float t2 = v * fmaf(GK2, v * v, GK1);
    float en = EXP2F(-t2);
    return v * __builtin_amdgcn_rcpf(1.0f + en);
}

__device__ __forceinline__ bf16x8 loadfrag(const __bf16* p) {
    return *reinterpret_cast<const bf16x8*>(p);
}
__device__ __forceinline__ bf16x8 loadfrag(const float* p) {
    f32x4 a = *reinterpret_cast<const f32x4*>(p);
    f32x4 b = *reinterpret_cast<const f32x4*>(p + 4);
    bf16x8 r;
#pragma unroll
    for (int i = 0; i < 4; ++i) { r[i] = (__bf16)a[i]; r[4 + i] = (__bf16)b[i]; }
    return r;
}

template<typename T>
__device__ __forceinline__ void load8f(const T* p, float* o);
template<>
__device__ __forceinline__ void load8f<__bf16>(const __bf16* p, float* o) {
    bf16x8 r = *reinterpret_cast<const bf16x8*>(p);
#pragma unroll
    for (int i = 0; i < 8; ++i) o[i] = (float)r[i];
}
template<>
__device__ __forceinline__ void load8f<float>(const float* p, float* o) {
    f32x4 a = *reinterpret_cast<const f32x4*>(p);
    f32x4 b = *reinterpret_cast<const f32x4*>(p + 4);
#pragma unroll
    for (int i = 0; i < 4; ++i) { o[i] = a[i]; o[4 + i] = b[i]; }
}

// paired epilogue-x load: features 2c and 2c+1 are adjacent in memory
__device__ __forceinline__ void load2f(const float* p, float& a, float& b) {
    const float2 v = *reinterpret_cast<const float2*>(p);
    a = v.x; b = v.y;
}
__device__ __forceinline__ void load2f(const __bf16* p, float& a, float& b) {
    u32 w = *reinterpret_cast<const u32*>(p);
    a = bf2f((u16)(w & 0xffffu)); b = bf2f((u16)(w >> 16));
}

// Per-wave dtype self-detect (f32-as-u16 low halves: ~25% have bf16-exp>=0xC0; true
// bf16 N(0,1): none). P(miss) < 1e-14 over 128 samples.
__device__ __forceinline__ int detect_isf(const void* x) {
    const int lane = threadIdx.x & 63;
    u32 w0 = ((const u32*)x)[lane];
    u32 w1 = ((const u32*)x)[64 + lane];
    int hit = ((((w0 >> 7) & 0xFFu) >= 0xC0u) || (((w1 >> 7) & 0xFFu) >= 0xC0u)) ? 1 : 0;
    return __ballot(hit) != 0ull;
}

// VALU-pipe rotation-add over each 16-lane row (DPP row_ror:N)
template<int CTRL>
__device__ __forceinline__ float dpp_rot_add(float v) {
    int s = __builtin_amdgcn_update_dpp(0, __builtin_bit_cast(int, v), CTRL, 0xF, 0xF, false);
    return v + __builtin_bit_cast(float, s);
}
__device__ __forceinline__ float row_reduce_add(float v) {
    v = dpp_rot_add<0x121>(v);   // row_ror:1
    v = dpp_rot_add<0x122>(v);   // row_ror:2
    v = dpp_rot_add<0x124>(v);   // row_ror:4
    v = dpp_rot_add<0x128>(v);   // row_ror:8
    return v;
}

// ---- stats: column sums/sumsq of h_pre = x @ w_in^T into 16 sharded copies.
// All 4 tile loads hoisted ahead of the MFMA chain (64 B/lane in flight).
// Block p reads rows [256p, 256p+256) -- the row->XCD mapping main recycles.
template<typename T>
__device__ __forceinline__ void stats_body(const T* __restrict__ x,
                                           const T* __restrict__ w_in,
                                           float* __restrict__ ws,
                                           float* __restrict__ red) {
    const int lane = threadIdx.x & 63;
    const int wave = threadIdx.x >> 6;
    const int c = lane & 15;
    const int q = lane >> 4;

    const int wid = blockIdx.x * 4 + wave;  // 0..8191, 64 rows each

    // issue ALL global loads first: 4 x-tiles + w_in fragments
    bf16x8 a1[4];
#pragma unroll
    for (int t = 0; t < 4; ++t) {
        const long row0 = ((long)wid * 4 + t) * 16;
        a1[t] = loadfrag(x + (row0 + c) * 32 + q * 8);
    }
    bf16x8 b1[4];
#pragma unroll
    for (int nt = 0; nt < 4; ++nt)
        b1[nt] = loadfrag(w_in + (nt * 16 + c) * 32 + q * 8);

    float accs[4][4], accq[4][4];
#pragma unroll
    for (int nt = 0; nt < 4; ++nt)
#pragma unroll
        for (int r = 0; r < 4; ++r) { accs[nt][r] = 0.f; accq[nt][r] = 0.f; }

#pragma unroll
    for (int t = 0; t < 4; ++t) {
#pragma unroll
        for (int nt = 0; nt < 4; ++nt) {
            f32x4 z = {0.f, 0.f, 0.f, 0.f};
            f32x4 acc = __builtin_amdgcn_mfma_f32_16x16x32_bf16(a1[t], b1[nt], z, 0, 0, 0);
#pragma unroll
            for (int r = 0; r < 4; ++r) {
                float v = acc[r];
                accs[nt][r] += v;
                accq[nt][r] += v * v;
            }
        }
    }
    for (int i = threadIdx.x; i < 128; i += 256) red[i] = 0.f;
    __syncthreads();
#pragma unroll
    for (int nt = 0; nt < 4; ++nt) {
        float s  = accs[nt][0] + accs[nt][1] + accs[nt][2] + accs[nt][3];
        float sq = accq[nt][0] + accq[nt][1] + accq[nt][2] + accq[nt][3];
        s  += __shfl_xor(s, 16);  s  += __shfl_xor(s, 32);
        sq += __shfl_xor(sq, 16); sq += __shfl_xor(sq, 32);
        if (q == 0) {
            atomicAdd(&red[nt * 16 + c], s);
            atomicAdd(&red[64 + nt * 16 + c], sq);
        }
    }
    __syncthreads();
    float* shard = ws + (blockIdx.x & (NSHADOW - 1)) * 128;
    for (int i = threadIdx.x; i < 128; i += 256) atomicAdd(&shard[i], red[i]);
}

__global__ __launch_bounds__(256) void stats_kernel(
    const void* x, const void* w_in,
    const void* w_fi, const void* b_fi, const void* w_fs, const void* b_fs,
    const void* w_lc, const void* b_lc, float* __restrict__ ws)
{
    const int isf = detect_isf(x);
    const int tid = threadIdx.x;

    // stats-independent weight pack (blocks 0-3): w2 frags in FINAL slot order.
    if (blockIdx.x < 3) {
        const int k = blockIdx.x * 256 + tid;            // 0..767
        const int f = k >> 6, l = k & 63, cc = l & 15, qq = l >> 4;
        const int nt = f >> 1, kt = f & 1;
        const int hb = kt * 32 + qq * 8;
        u16x8 v8;
        if (nt < 2) {
            const int ft = 2 * cc + nt;
#pragma unroll
            for (int j = 0; j < 8; ++j)
                v8[j] = f2bf(ldany(w_fi, ft * 64 + hb + j, isf) * K_LOG2E);
        } else if (nt < 4) {
            const int ft = 2 * cc + (nt - 2);
#pragma unroll
            for (int j = 0; j < 8; ++j)
                v8[j] = f2bf(ldany(w_fs, ft * 64 + hb + j, isf) * K_LOG2E);
        } else {
            const int r0 = ((nt == 4) ? 0 : 20) + cc;
#pragma unroll
            for (int j = 0; j < 8; ++j)
                v8[j] = (cc < 10) ? f2bf(ldany(w_lc, (long)r0 * 64 + hb + j, isf)
                                       + ldany(w_lc, (long)(r0 + 10) * 64 + hb + j, isf))
                                  : (u16)0;
        }
        *reinterpret_cast<u16x8*>((u16*)((char*)ws + 16384) + k * 8) = v8;
    } else if (blockIdx.x == 3) {
        float* biasp = (float*)((char*)ws + 28672);
        for (int idx = tid; idx < 384; idx += 256) {
            const int p = idx >> 2, nt = p >> 4, cc = p & 15;
            float v = 0.f;
            if      (nt == 0) v = ldany(b_fi, 2 * cc,     isf) * K_LOG2E;
            else if (nt == 1) v = ldany(b_fi, 2 * cc + 1, isf) * K_LOG2E;
            else if (nt == 2) v = ldany(b_fs, 2 * cc,     isf) * K_LOG2E;
            else if (nt == 3) v = ldany(b_fs, 2 * cc + 1, isf) * K_LOG2E;
            else if (nt == 4) v = (cc < 10) ? ldany(b_lc, cc,      isf) + ldany(b_lc, 10 + cc, isf) : 0.f;
            else              v = (cc < 10) ? ldany(b_lc, 20 + cc, isf) + ldany(b_lc, 30 + cc, isf) : 0.f;
            biasp[idx] = v;
        }
    }

    __shared__ float red[128];
    if (isf) stats_body<float>((const float*)x, (const float*)w_in, ws, red);
    else     stats_body<__bf16>((const __bf16*)x, (const __bf16*)w_in, ws, red);
    // fence-free end: no election, no tail. Dispatch boundary publishes everything.
}

// ---- main: per-block prologue (2 barriers) then 8 software-pipelined tiles.
// GEMM1 transposed (A=scaled-W1 rows permuted by phi, B=x^T) so its C-layout
// output IS the A-fragment of GEMM2. BN shift rides GEMM1's C operand; GEMM2
// biases ride GEMM2's C operand. fi/fs pre-scaled by log2e -> bare v_exp.
// a1 prefetch depth 2. XCD-aligned row remap: block m reads stats blocks
// {a, a+8}, a=16*(m>>3)+(m&7) -> x reads hit the same-XCD L2 stats populated.
template<typename T>
__device__ __forceinline__ void main_body(
    const T* __restrict__ x, const T* __restrict__ w_in,
    const T* __restrict__ bn_g, const T* __restrict__ bn_b,
    const float* __restrict__ ws, T* __restrict__ out,
    char* __restrict__ lds, float* __restrict__ sums,
    float* __restrict__ shs)
{
    const int tid = threadIdx.x;
    const int lane = tid & 63;
    const int wave = tid >> 6;
    const int c = lane & 15;
    const int q = lane >> 4;

    // XCD-aligned segment pick: both segments = blockIdx (mod 8) -> same XCD's
    // L2 that stats block a / a+8 populated. Bijective onto [0, 2048) segments.
    const long a = 16L * (blockIdx.x >> 3) + (blockIdx.x & 7);
    const long seg = (wave < 2) ? a : a + 8;
    const long rowb = seg * 256 + (long)(wave & 1) * 128;   // 128 rows, 8 tiles

    // issue tiles 0 and 1's a1 immediately (hide under the whole prologue)
    bf16x8 a1cur = loadfrag(x + (rowb + c) * 32 + q * 8);
    bf16x8 a1nx1 = loadfrag(x + (rowb + 16 + c) * 32 + q * 8);

    // phase A: linear copy of stats-packed w2+bias blob (13824 B = 864 x 16 B)
    // and collapse of the 16 sharded stat copies. Independent, no barrier between.
    {
        const f32x4* gsrc = (const f32x4*)((const char*)ws + 16384);
        f32x4* ldst = (f32x4*)(lds + 4096);
        for (int i = tid; i < 864; i += 256) ldst[i] = gsrc[i];
    }
    if (tid < 128) {
        float s = 0.f;
#pragma unroll
        for (int k = 0; k < NSHADOW; ++k) s += ws[k * 128 + tid];
        sums[tid] = s;
    }
    __syncthreads();

    // phase B: w1 scale-pack with INLINE scl (each thread recomputes its row's
    // BN scale from sums); shs (C-operand-layout BN shifts) by tid<64.
    {
        const int nt = tid >> 6, l = tid & 63, cc = l & 15, qq = l >> 4;
        const int row = 32 * (nt >> 1) + 8 * (cc >> 2) + 4 * (nt & 1) + (cc & 3);
        float mu  = sums[row] * (1.0f / NB);
        float var = fmaxf(sums[64 + row] * (1.0f / NB) - mu * mu, 0.0f);
        float s   = (float)bn_g[row] * rsqrtf(var + EPSI);
        float w8[8];
        load8f(w_in + row * 32 + qq * 8, w8);
        u16x8 v8;
#pragma unroll
        for (int j = 0; j < 8; ++j) v8[j] = f2bf(w8[j] * s);
        *reinterpret_cast<u16x8*>(lds + tid * 16) = v8;
    }
    if (tid < 64) {
        const int qq = tid >> 4, nt = (tid >> 2) & 3, r = tid & 3;
        const int ft = 32 * (nt >> 1) + 8 * qq + 4 * (nt & 1) + r;
        float mu  = sums[ft] * (1.0f / NB);
        float var = fmaxf(sums[64 + ft] * (1.0f / NB) - mu * mu, 0.0f);
        float s   = (float)bn_g[ft] * rsqrtf(var + EPSI);
        shs[tid] = (float)bn_b[ft] - mu * s;
    }
    __syncthreads();

    // phase C: persistent w1 fragments, then the pipelined tile loop
    bf16x8 w1r[4];
#pragma unroll
    for (int nt = 0; nt < 4; ++nt)
        w1r[nt] = *reinterpret_cast<const bf16x8*>((const u16*)lds + (nt * 64 + lane) * 8);

#pragma unroll 2
    for (int t = 0; t < 8; ++t) {
        // prefetch tile t+2's a1 (B-frag of GEMM1)
        bf16x8 a1nx2;
        if (t < 6) a1nx2 = loadfrag(x + (rowb + (long)(t + 2) * 16 + c) * 32 + q * 8);

        // opaque zero offset: stops the compiler hoisting the LARGE LDS arrays
        // (w2/sh/bias) back into persistent registers across tiles
        u32 tweak = 0;
        asm volatile("" : "+v"(tweak));
        const u16*   w2b = (const u16*)(lds + 4096) + tweak;
        const float* bb  = (const float*)(lds + 16384) + tweak;
        const float* shb = shs + tweak;

        const long row0 = rowb + (long)t * 16;

        // epilogue x pairs (features 2c, 2c+1) in C-layout; L1-hot (a1-warmed)
        float xv0[4], xv1[4];
#pragma unroll
        for (int r = 0; r < 4; ++r)
            load2f(x + (row0 + q * 4 + r) * 32 + 2 * c, xv0[r], xv1[r]);

        // GEMM1^T with BN shift as the C operand:
        // lane(c,q) reg r = s*h_pre[batch c][feat phi(nt,4q+r)] + shift(...)
        f32x4 h4[4];
#pragma unroll
        for (int nt = 0; nt < 4; ++nt) {
            f32x4 sh = *reinterpret_cast<const f32x4*>(shb + q * 16 + nt * 4);
            h4[nt] = __builtin_amdgcn_mfma_f32_16x16x32_bf16(w1r[nt], a1cur, sh, 0, 0, 0);
        }

        // gelu; pack: a2_0[j=4nt+r]=g[nt][r] (nt 0..1), a2_1: nt 2..3
        bf16x8 a2_0, a2_1;
#pragma unroll
        for (int nt = 0; nt < 2; ++nt) {
#pragma unroll
            for (int r = 0; r < 4; ++r) {
                a2_0[nt * 4 + r] = (__bf16)fast_gelu(h4[nt][r]);
                a2_1[nt * 4 + r] = (__bf16)fast_gelu(h4[2 + nt][r]);
            }
        }

        // GEMM2 with bias as the C operand
        f32x4 acc[6];
#pragma unroll
        for (int nt = 0; nt < 6; ++nt) {
            bf16x8 f0 = *reinterpret_cast<const bf16x8*>(w2b + ((nt * 2 + 0) * 64 + lane) * 8);
            bf16x8 f1 = *reinterpret_cast<const bf16x8*>(w2b + ((nt * 2 + 1) * 64 + lane) * 8);
            f32x4 bz = *reinterpret_cast<const f32x4*>(bb + (nt * 16 + c) * 4);
            acc[nt] = __builtin_amdgcn_mfma_f32_16x16x32_bf16(a2_0, f0, bz, 0, 0, 0);
            acc[nt] = __builtin_amdgcn_mfma_f32_16x16x32_bf16(a2_1, f1, acc[nt], 0, 0, 0);
        }

#pragma unroll
        for (int r = 0; r < 4; ++r) {
            // acc0/1 = log2e*(fi+b): bare exp2. No max-subtraction: |fi| << 87.
            float e0 = EXP2F(acc[0][r]);
            float e1 = EXP2F(acc[1][r]);
            // acc2/3 = log2e*(fs+b): t = log2e*(x - fs), so dp is log2e*<smx, x-fs>
            float t0 = fmaf(K_LOG2E, xv0[r], -acc[2][r]);
            float t1 = fmaf(K_LOG2E, xv1[r], -acc[3][r]);
            float es = row_reduce_add(e0 + e1);
            float dp = row_reduce_add(fmaf(e1, t1, e0 * t0));
            float d2 = dp * __builtin_amdgcn_rcpf(es);          // = log2e * d
            float sd = __builtin_amdgcn_rcpf(1.0f + EXP2F(-d2));
            float o  = sd * fmaf(sd, acc[4][r] - acc[5][r], acc[5][r]); // sd^2 u + sd(1-sd) v
            if (c < 10) out[(row0 + q * 4 + r) * 10 + c] = (T)o;
        }

        a1cur = a1nx1;
        a1nx1 = a1nx2;
    }
}

// (256,4): reg cap 128 (~64 used). LDS ~19 KB. Grid 1024 = 4 blocks/CU,
// one generation, 8 tiles/wave (R7 best config) + XCD-aligned row remap.
__global__ __launch_bounds__(256, 4) void main_kernel(
    const void* x, const void* w_in, const void* bn_g, const void* bn_b,
    const float* __restrict__ ws, void* outv)
{
    __shared__ __attribute__((aligned(16))) char lds[17920];
    __shared__ float sums[128], shs[64];
    if (detect_isf(x))
        main_body<float>((const float*)x, (const float*)w_in, (const float*)bn_g,
                         (const float*)bn_b, ws, (float*)outv, lds, sums, shs);
    else
        main_body<__bf16>((const __bf16*)x, (const __bf16*)w_in, (const __bf16*)bn_g,
                          (const __bf16*)bn_b, ws, (__bf16*)outv, lds, sums, shs);
}

extern "C" void kernel_launch(void* const* d_in, const int* in_sizes, int n_in,
                              void* d_out, int out_size, void* d_ws, size_t ws_size,
                              hipStream_t stream) {
    float* ws = (float*)d_ws;
    hipMemsetAsync(d_ws, 0, 8192, stream);  // zero shard accumulators
    stats_kernel<<<2048, 256, 0, stream>>>(d_in[0], d_in[1],
                                           d_in[5], d_in[6], d_in[7], d_in[8],
                                           d_in[9], d_in[10], ws);
    main_kernel<<<1024, 256, 0, stream>>>(d_in[0], d_in[1], d_in[3], d_in[4],
                                          ws, d_out);
}

// Round 11
// 151.005 us; speedup vs baseline: 1.0234x; 1.0052x over previous
//
#include <hip/hip_runtime.h>

typedef __attribute__((ext_vector_type(8))) __bf16 bf16x8;
typedef __attribute__((ext_vector_type(4))) float f32x4;
typedef __attribute__((ext_vector_type(8))) unsigned short u16x8;
typedef unsigned short u16;
typedef unsigned int u32;

#define NB 524288
#define EPSI 1e-5f
#define NSHADOW 16   // sharded stat accumulators: 16 x 128 floats
#define K_LOG2E 1.4426950408889634f

// 2-dispatch structure (R5: grid-wide counter election = ~32 us serialized RMWs;
// R2-R4: separate 1-block finalize dispatch = ~6-8 us. Both avoided.)
//
// ws byte layout:
//   [0, 8192)       : 16 shard copies of the 128 stat floats (sum, sumsq)
//   [16384, 28672)  : w2 frags, 768 slots x 16 B, FINAL slot order
//   [28672, 30208)  : biasv, 384 f32 (96 biases broadcast x4, GEMM2 C layout)
// Stats-pack (blocks 0-3) is stats-INDEPENDENT. Visibility via dispatch boundary.
//
// R7 (best, 151.5): main 1024x8 pipelined. R8-R10: occupancy/prefetch/XCD-remap
// all within noise. R11 lever: main WRITE_SIZE = 2x output size (partial-line
// scalar stores, 40/tile) -> per-wave LDS repack + lane<20 dwordx4 coalesced
// writeback (320 B/tile contiguous, line-aligned). Wave-local, no barrier.

__device__ __forceinline__ float bf2f(u16 h) {
    union { u32 u; float f; } cv; cv.u = ((u32)h) << 16; return cv.f;
}
__device__ __forceinline__ u16 f2bf(float f) {
    __bf16 b = (__bf16)f; return __builtin_bit_cast(u16, b);
}
__device__ __forceinline__ float ldany(const void* p, long i, int isf) {
    return isf ? ((const float*)p)[i] : bf2f(((const u16*)p)[i]);
}

#if __has_builtin(__builtin_amdgcn_exp2f)
#define EXP2F(x) __builtin_amdgcn_exp2f(x)
#else
#define EXP2F(x) exp2f(x)
#endif

// gelu_tanh with log2e folded into the polynomial:
// g = v / (1 + exp2(-v*(GK1 + GK2*v^2))), GK1 = 1.5957691*log2e, GK2 = GK1*0.044715
#define GK1 2.3022082f
#define GK2 0.10294324f
__device__ __forceinline__ float fast_gelu(float v) {
    float t2 = v * fmaf(GK2, v * v, GK1);
    float en = EXP2F(-t2);
    return v * __builtin_amdgcn_rcpf(1.0f + en);
}

__device__ __forceinline__ bf16x8 loadfrag(const __bf16* p) {
    return *reinterpret_cast<const bf16x8*>(p);
}
__device__ __forceinline__ bf16x8 loadfrag(const float* p) {
    f32x4 a = *reinterpret_cast<const f32x4*>(p);
    f32x4 b = *reinterpret_cast<const f32x4*>(p + 4);
    bf16x8 r;
#pragma unroll
    for (int i = 0; i < 4; ++i) { r[i] = (__bf16)a[i]; r[4 + i] = (__bf16)b[i]; }
    return r;
}

template<typename T>
__device__ __forceinline__ void load8f(const T* p, float* o);
template<>
__device__ __forceinline__ void load8f<__bf16>(const __bf16* p, float* o) {
    bf16x8 r = *reinterpret_cast<const bf16x8*>(p);
#pragma unroll
    for (int i = 0; i < 8; ++i) o[i] = (float)r[i];
}
template<>
__device__ __forceinline__ void load8f<float>(const float* p, float* o) {
    f32x4 a = *reinterpret_cast<const f32x4*>(p);
    f32x4 b = *reinterpret_cast<const f32x4*>(p + 4);
#pragma unroll
    for (int i = 0; i < 4; ++i) { o[i] = a[i]; o[4 + i] = b[i]; }
}

// paired epilogue-x load: features 2c and 2c+1 are adjacent in memory
__device__ __forceinline__ void load2f(const float* p, float& a, float& b) {
    const float2 v = *reinterpret_cast<const float2*>(p);
    a = v.x; b = v.y;
}
__device__ __forceinline__ void load2f(const __bf16* p, float& a, float& b) {
    u32 w = *reinterpret_cast<const u32*>(p);
    a = bf2f((u16)(w & 0xffffu)); b = bf2f((u16)(w >> 16));
}

// Per-wave dtype self-detect (f32-as-u16 low halves: ~25% have bf16-exp>=0xC0; true
// bf16 N(0,1): none). P(miss) < 1e-14 over 128 samples.
__device__ __forceinline__ int detect_isf(const void* x) {
    const int lane = threadIdx.x & 63;
    u32 w0 = ((const u32*)x)[lane];
    u32 w1 = ((const u32*)x)[64 + lane];
    int hit = ((((w0 >> 7) & 0xFFu) >= 0xC0u) || (((w1 >> 7) & 0xFFu) >= 0xC0u)) ? 1 : 0;
    return __ballot(hit) != 0ull;
}

// VALU-pipe rotation-add over each 16-lane row (DPP row_ror:N)
template<int CTRL>
__device__ __forceinline__ float dpp_rot_add(float v) {
    int s = __builtin_amdgcn_update_dpp(0, __builtin_bit_cast(int, v), CTRL, 0xF, 0xF, false);
    return v + __builtin_bit_cast(float, s);
}
__device__ __forceinline__ float row_reduce_add(float v) {
    v = dpp_rot_add<0x121>(v);   // row_ror:1
    v = dpp_rot_add<0x122>(v);   // row_ror:2
    v = dpp_rot_add<0x124>(v);   // row_ror:4
    v = dpp_rot_add<0x128>(v);   // row_ror:8
    return v;
}

// ---- stats: column sums/sumsq of h_pre = x @ w_in^T into 16 sharded copies.
// All 4 tile loads hoisted ahead of the MFMA chain (64 B/lane in flight).
// Block p reads rows [256p, 256p+256) -- the row->XCD mapping main recycles.
template<typename T>
__device__ __forceinline__ void stats_body(const T* __restrict__ x,
                                           const T* __restrict__ w_in,
                                           float* __restrict__ ws,
                                           float* __restrict__ red) {
    const int lane = threadIdx.x & 63;
    const int wave = threadIdx.x >> 6;
    const int c = lane & 15;
    const int q = lane >> 4;

    const int wid = blockIdx.x * 4 + wave;  // 0..8191, 64 rows each

    // issue ALL global loads first: 4 x-tiles + w_in fragments
    bf16x8 a1[4];
#pragma unroll
    for (int t = 0; t < 4; ++t) {
        const long row0 = ((long)wid * 4 + t) * 16;
        a1[t] = loadfrag(x + (row0 + c) * 32 + q * 8);
    }
    bf16x8 b1[4];
#pragma unroll
    for (int nt = 0; nt < 4; ++nt)
        b1[nt] = loadfrag(w_in + (nt * 16 + c) * 32 + q * 8);

    float accs[4][4], accq[4][4];
#pragma unroll
    for (int nt = 0; nt < 4; ++nt)
#pragma unroll
        for (int r = 0; r < 4; ++r) { accs[nt][r] = 0.f; accq[nt][r] = 0.f; }

#pragma unroll
    for (int t = 0; t < 4; ++t) {
#pragma unroll
        for (int nt = 0; nt < 4; ++nt) {
            f32x4 z = {0.f, 0.f, 0.f, 0.f};
            f32x4 acc = __builtin_amdgcn_mfma_f32_16x16x32_bf16(a1[t], b1[nt], z, 0, 0, 0);
#pragma unroll
            for (int r = 0; r < 4; ++r) {
                float v = acc[r];
                accs[nt][r] += v;
                accq[nt][r] += v * v;
            }
        }
    }
    for (int i = threadIdx.x; i < 128; i += 256) red[i] = 0.f;
    __syncthreads();
#pragma unroll
    for (int nt = 0; nt < 4; ++nt) {
        float s  = accs[nt][0] + accs[nt][1] + accs[nt][2] + accs[nt][3];
        float sq = accq[nt][0] + accq[nt][1] + accq[nt][2] + accq[nt][3];
        s  += __shfl_xor(s, 16);  s  += __shfl_xor(s, 32);
        sq += __shfl_xor(sq, 16); sq += __shfl_xor(sq, 32);
        if (q == 0) {
            atomicAdd(&red[nt * 16 + c], s);
            atomicAdd(&red[64 + nt * 16 + c], sq);
        }
    }
    __syncthreads();
    float* shard = ws + (blockIdx.x & (NSHADOW - 1)) * 128;
    for (int i = threadIdx.x; i < 128; i += 256) atomicAdd(&shard[i], red[i]);
}

__global__ __launch_bounds__(256) void stats_kernel(
    const void* x, const void* w_in,
    const void* w_fi, const void* b_fi, const void* w_fs, const void* b_fs,
    const void* w_lc, const void* b_lc, float* __restrict__ ws)
{
    const int isf = detect_isf(x);
    const int tid = threadIdx.x;

    // stats-independent weight pack (blocks 0-3): w2 frags in FINAL slot order.
    if (blockIdx.x < 3) {
        const int k = blockIdx.x * 256 + tid;            // 0..767
        const int f = k >> 6, l = k & 63, cc = l & 15, qq = l >> 4;
        const int nt = f >> 1, kt = f & 1;
        const int hb = kt * 32 + qq * 8;
        u16x8 v8;
        if (nt < 2) {
            const int ft = 2 * cc + nt;
#pragma unroll
            for (int j = 0; j < 8; ++j)
                v8[j] = f2bf(ldany(w_fi, ft * 64 + hb + j, isf) * K_LOG2E);
        } else if (nt < 4) {
            const int ft = 2 * cc + (nt - 2);
#pragma unroll
            for (int j = 0; j < 8; ++j)
                v8[j] = f2bf(ldany(w_fs, ft * 64 + hb + j, isf) * K_LOG2E);
        } else {
            const int r0 = ((nt == 4) ? 0 : 20) + cc;
#pragma unroll
            for (int j = 0; j < 8; ++j)
                v8[j] = (cc < 10) ? f2bf(ldany(w_lc, (long)r0 * 64 + hb + j, isf)
                                       + ldany(w_lc, (long)(r0 + 10) * 64 + hb + j, isf))
                                  : (u16)0;
        }
        *reinterpret_cast<u16x8*>((u16*)((char*)ws + 16384) + k * 8) = v8;
    } else if (blockIdx.x == 3) {
        float* biasp = (float*)((char*)ws + 28672);
        for (int idx = tid; idx < 384; idx += 256) {
            const int p = idx >> 2, nt = p >> 4, cc = p & 15;
            float v = 0.f;
            if      (nt == 0) v = ldany(b_fi, 2 * cc,     isf) * K_LOG2E;
            else if (nt == 1) v = ldany(b_fi, 2 * cc + 1, isf) * K_LOG2E;
            else if (nt == 2) v = ldany(b_fs, 2 * cc,     isf) * K_LOG2E;
            else if (nt == 3) v = ldany(b_fs, 2 * cc + 1, isf) * K_LOG2E;
            else if (nt == 4) v = (cc < 10) ? ldany(b_lc, cc,      isf) + ldany(b_lc, 10 + cc, isf) : 0.f;
            else              v = (cc < 10) ? ldany(b_lc, 20 + cc, isf) + ldany(b_lc, 30 + cc, isf) : 0.f;
            biasp[idx] = v;
        }
    }

    __shared__ float red[128];
    if (isf) stats_body<float>((const float*)x, (const float*)w_in, ws, red);
    else     stats_body<__bf16>((const __bf16*)x, (const __bf16*)w_in, ws, red);
    // fence-free end: no election, no tail. Dispatch boundary publishes everything.
}

// ---- main: per-block prologue (2 barriers) then 8 software-pipelined tiles.
// GEMM1 transposed (A=scaled-W1 rows permuted by phi, B=x^T) so its C-layout
// output IS the A-fragment of GEMM2. BN shift rides GEMM1's C operand; GEMM2
// biases ride GEMM2's C operand. fi/fs pre-scaled by log2e -> bare v_exp.
// a1 prefetch depth 2. XCD-aligned row remap: block m reads stats blocks
// {a, a+8}, a=16*(m>>3)+(m&7) -> x reads hit the same-XCD L2 stats populated.
// Output via per-wave LDS repack -> lane<10*sizeof(T) dwordx4 coalesced stores
// (R11: scalar 2B stores caused exactly 2x WRITE_SIZE inflation).
template<typename T>
__device__ __forceinline__ void main_body(
    const T* __restrict__ x, const T* __restrict__ w_in,
    const T* __restrict__ bn_g, const T* __restrict__ bn_b,
    const float* __restrict__ ws, T* __restrict__ out,
    char* __restrict__ lds, float* __restrict__ sums,
    float* __restrict__ shs)
{
    const int tid = threadIdx.x;
    const int lane = tid & 63;
    const int wave = tid >> 6;
    const int c = lane & 15;
    const int q = lane >> 4;

    // XCD-aligned segment pick: both segments = blockIdx (mod 8) -> same XCD's
    // L2 that stats block a / a+8 populated. Bijective onto [0, 2048) segments.
    const long a = 16L * (blockIdx.x >> 3) + (blockIdx.x & 7);
    const long seg = (wave < 2) ? a : a + 8;
    const long rowb = seg * 256 + (long)(wave & 1) * 128;   // 128 rows, 8 tiles

    // per-wave output staging scratch (16 rows x 10 cols x sizeof(T))
    char* scr = lds + 17920 + wave * 2560;

    // issue tiles 0 and 1's a1 immediately (hide under the whole prologue)
    bf16x8 a1cur = loadfrag(x + (rowb + c) * 32 + q * 8);
    bf16x8 a1nx1 = loadfrag(x + (rowb + 16 + c) * 32 + q * 8);

    // phase A: linear copy of stats-packed w2+bias blob (13824 B = 864 x 16 B)
    // and collapse of the 16 sharded stat copies. Independent, no barrier between.
    {
        const f32x4* gsrc = (const f32x4*)((const char*)ws + 16384);
        f32x4* ldst = (f32x4*)(lds + 4096);
        for (int i = tid; i < 864; i += 256) ldst[i] = gsrc[i];
    }
    if (tid < 128) {
        float s = 0.f;
#pragma unroll
        for (int k = 0; k < NSHADOW; ++k) s += ws[k * 128 + tid];
        sums[tid] = s;
    }
    __syncthreads();

    // phase B: w1 scale-pack with INLINE scl (each thread recomputes its row's
    // BN scale from sums); shs (C-operand-layout BN shifts) by tid<64.
    {
        const int nt = tid >> 6, l = tid & 63, cc = l & 15, qq = l >> 4;
        const int row = 32 * (nt >> 1) + 8 * (cc >> 2) + 4 * (nt & 1) + (cc & 3);
        float mu  = sums[row] * (1.0f / NB);
        float var = fmaxf(sums[64 + row] * (1.0f / NB) - mu * mu, 0.0f);
        float s   = (float)bn_g[row] * rsqrtf(var + EPSI);
        float w8[8];
        load8f(w_in + row * 32 + qq * 8, w8);
        u16x8 v8;
#pragma unroll
        for (int j = 0; j < 8; ++j) v8[j] = f2bf(w8[j] * s);
        *reinterpret_cast<u16x8*>(lds + tid * 16) = v8;
    }
    if (tid < 64) {
        const int qq = tid >> 4, nt = (tid >> 2) & 3, r = tid & 3;
        const int ft = 32 * (nt >> 1) + 8 * qq + 4 * (nt & 1) + r;
        float mu  = sums[ft] * (1.0f / NB);
        float var = fmaxf(sums[64 + ft] * (1.0f / NB) - mu * mu, 0.0f);
        float s   = (float)bn_g[ft] * rsqrtf(var + EPSI);
        shs[tid] = (float)bn_b[ft] - mu * s;
    }
    __syncthreads();

    // phase C: persistent w1 fragments, then the pipelined tile loop
    bf16x8 w1r[4];
#pragma unroll
    for (int nt = 0; nt < 4; ++nt)
        w1r[nt] = *reinterpret_cast<const bf16x8*>((const u16*)lds + (nt * 64 + lane) * 8);

#pragma unroll 2
    for (int t = 0; t < 8; ++t) {
        // prefetch tile t+2's a1 (B-frag of GEMM1)
        bf16x8 a1nx2;
        if (t < 6) a1nx2 = loadfrag(x + (rowb + (long)(t + 2) * 16 + c) * 32 + q * 8);

        // opaque zero offset: stops the compiler hoisting the LARGE LDS arrays
        // (w2/sh/bias) back into persistent registers across tiles
        u32 tweak = 0;
        asm volatile("" : "+v"(tweak));
        const u16*   w2b = (const u16*)(lds + 4096) + tweak;
        const float* bb  = (const float*)(lds + 16384) + tweak;
        const float* shb = shs + tweak;

        const long row0 = rowb + (long)t * 16;

        // epilogue x pairs (features 2c, 2c+1) in C-layout; L1-hot (a1-warmed)
        float xv0[4], xv1[4];
#pragma unroll
        for (int r = 0; r < 4; ++r)
            load2f(x + (row0 + q * 4 + r) * 32 + 2 * c, xv0[r], xv1[r]);

        // GEMM1^T with BN shift as the C operand:
        // lane(c,q) reg r = s*h_pre[batch c][feat phi(nt,4q+r)] + shift(...)
        f32x4 h4[4];
#pragma unroll
        for (int nt = 0; nt < 4; ++nt) {
            f32x4 sh = *reinterpret_cast<const f32x4*>(shb + q * 16 + nt * 4);
            h4[nt] = __builtin_amdgcn_mfma_f32_16x16x32_bf16(w1r[nt], a1cur, sh, 0, 0, 0);
        }

        // gelu; pack: a2_0[j=4nt+r]=g[nt][r] (nt 0..1), a2_1: nt 2..3
        bf16x8 a2_0, a2_1;
#pragma unroll
        for (int nt = 0; nt < 2; ++nt) {
#pragma unroll
            for (int r = 0; r < 4; ++r) {
                a2_0[nt * 4 + r] = (__bf16)fast_gelu(h4[nt][r]);
                a2_1[nt * 4 + r] = (__bf16)fast_gelu(h4[2 + nt][r]);
            }
        }

        // GEMM2 with bias as the C operand
        f32x4 acc[6];
#pragma unroll
        for (int nt = 0; nt < 6; ++nt) {
            bf16x8 f0 = *reinterpret_cast<const bf16x8*>(w2b + ((nt * 2 + 0) * 64 + lane) * 8);
            bf16x8 f1 = *reinterpret_cast<const bf16x8*>(w2b + ((nt * 2 + 1) * 64 + lane) * 8);
            f32x4 bz = *reinterpret_cast<const f32x4*>(bb + (nt * 16 + c) * 4);
            acc[nt] = __builtin_amdgcn_mfma_f32_16x16x32_bf16(a2_0, f0, bz, 0, 0, 0);
            acc[nt] = __builtin_amdgcn_mfma_f32_16x16x32_bf16(a2_1, f1, acc[nt], 0, 0, 0);
        }

#pragma unroll
        for (int r = 0; r < 4; ++r) {
            // acc0/1 = log2e*(fi+b): bare exp2. No max-subtraction: |fi| << 87.
            float e0 = EXP2F(acc[0][r]);
            float e1 = EXP2F(acc[1][r]);
            // acc2/3 = log2e*(fs+b): t = log2e*(x - fs), so dp is log2e*<smx, x-fs>
            float t0 = fmaf(K_LOG2E, xv0[r], -acc[2][r]);
            float t1 = fmaf(K_LOG2E, xv1[r], -acc[3][r]);
            float es = row_reduce_add(e0 + e1);
            float dp = row_reduce_add(fmaf(e1, t1, e0 * t0));
            float d2 = dp * __builtin_amdgcn_rcpf(es);          // = log2e * d
            float sd = __builtin_amdgcn_rcpf(1.0f + EXP2F(-d2));
            float o  = sd * fmaf(sd, acc[4][r] - acc[5][r], acc[5][r]); // sd^2 u + sd(1-sd) v
            // stage into wave-local LDS scratch (16 rows x 10 cols)
            if (c < 10) ((T*)scr)[(q * 4 + r) * 10 + c] = (T)o;
        }

        // coalesced writeback: 320 B (bf16) / 640 B (f32) contiguous, 16 B/lane.
        // Wave-local LDS RAW/WAR ordering via lgkmcnt (in-order DS per wave).
        {
            const int nst = 10 * (int)sizeof(T);   // 20 (bf16) or 40 (f32) lanes
            if (lane < nst) {
                f32x4 v = *reinterpret_cast<const f32x4*>(scr + lane * 16);
                *reinterpret_cast<f32x4*>((char*)out + row0 * 10 * (long)sizeof(T)
                                          + lane * 16) = v;
            }
        }

        a1cur = a1nx1;
        a1nx1 = a1nx2;
    }
}

// (256,4): reg cap 128 (~64 used). LDS 17920 + 4x2560 scratch = 28160 B
// (+sums/shs) -> 4 blocks/CU fine. Grid 1024 = 4 blocks/CU, one generation,
// 8 tiles/wave (R7 best config) + XCD-aligned row remap.
__global__ __launch_bounds__(256, 4) void main_kernel(
    const void* x, const void* w_in, const void* bn_g, const void* bn_b,
    const float* __restrict__ ws, void* outv)
{
    __shared__ __attribute__((aligned(16))) char lds[28160];
    __shared__ float sums[128], shs[64];
    if (detect_isf(x))
        main_body<float>((const float*)x, (const float*)w_in, (const float*)bn_g,
                         (const float*)bn_b, ws, (float*)outv, lds, sums, shs);
    else
        main_body<__bf16>((const __bf16*)x, (const __bf16*)w_in, (const __bf16*)bn_g,
                          (const __bf16*)bn_b, ws, (__bf16*)outv, lds, sums, shs);
}

extern "C" void kernel_launch(void* const* d_in, const int* in_sizes, int n_in,
                              void* d_out, int out_size, void* d_ws, size_t ws_size,
                              hipStream_t stream) {
    float* ws = (float*)d_ws;
    hipMemsetAsync(d_ws, 0, 8192, stream);  // zero shard accumulators
    stats_kernel<<<2048, 256, 0, stream>>>(d_in[0], d_in[1],
                                           d_in[5], d_in[6], d_in[7], d_in[8],
                                           d_in[9], d_in[10], ws);
    main_kernel<<<1024, 256, 0, stream>>>(d_in[0], d_in[1], d_in[3], d_in[4],
                                          ws, d_out);
}